// Round 9
// baseline (494.742 us; speedup 1.0000x reference)
//
#include <hip/hip_runtime.h>

// ConvMlp4d: conv4d(64->128) + bias + relu -> conv4d(128->64) + bias.
// R19: barrier-free direct-load design.
//   Evidence: R10-R18 (7 geometry/schedule/pinning/occupancy variants) all
//   deliver MfmaUtil x dur == const (~40% effective matrix throughput);
//   per-wave duty halves as waves double -> waves stall TOGETHER. No pipe
//   saturated (LDS 33%, L2 30%, VALU 15%, HBM 8%). Shared invariant: the
//   per-unit vmcnt(0)+s_barrier+LDS-staging convoy. The LDS tile is a PURE
//   COPY of chunk-planar global (no transpose, only halo zeros), so:
//   - NO LDS, NO global_load_lds, NO barriers, NO waitcnt asm
//   - each 64-thr block = ONE independent wave: stream B+A loads -> MFMA
//   - A direct from L2 (per-XCD working set ~2MB < 4MB; kw-overlap -> L1)
//   - halo: clamp address, lane-select zero (kw edges, j=0/5 rows)
//   - conv1 grid 4096 (COUT 4-split, 4 waves/SIMD), conv2 grid 2048
//     (COUT 2-split, 2 waves/SIMD) -> occupancy split is a TLP diagnostic
//   ws: x_t bf16 [2][65536][64] | h_t bf16 [2][65536][128] (chunk-planar:
//       [nb][tu][v][chunk=c/8][w][c%8])
//       w1t bf16 [81][4][128][16] | w2t bf16 [81][8][64][16]

using bf16x8 = __attribute__((ext_vector_type(8))) __bf16;
using f32x16 = __attribute__((ext_vector_type(16))) float;
using f32x4  = __attribute__((ext_vector_type(4))) float;

// ------- prep: x (2,64,65536) f32 -> x_t chunk-planar bf16 -------------------------
__global__ __launch_bounds__(256) void cvt_x(const float* __restrict__ x,
                                             __bf16* __restrict__ x_t) {
    __shared__ float lt[64][65];
    const int nb = blockIdx.y;
    const int p0 = blockIdx.x * 64;
    const int tu = p0 >> 10;
    const float* src = x + (size_t)nb * 64 * 65536;
    __bf16* dst = x_t + (size_t)nb * 65536 * 64;
    #pragma unroll
    for (int i = 0; i < 16; ++i) {
        int idx = i * 256 + threadIdx.x;
        int c = idx >> 6, p = idx & 63;
        lt[c][p] = src[(size_t)c * 65536 + p0 + p];
    }
    __syncthreads();
    #pragma unroll
    for (int it = 0; it < 2; ++it) {
        int idx = it * 256 + threadIdx.x;
        int pl = idx & 63;
        int chunk = idx >> 6;
        int p = p0 + pl;
        int v = (p >> 5) & 31, w = p & 31;
        bf16x8 pk;
        #pragma unroll
        for (int e = 0; e < 8; ++e)
            pk[e] = (__bf16)lt[chunk * 8 + e][pl];
        *(bf16x8*)(dst + (size_t)(tu * 32 + v) * 2048 + chunk * 256 + w * 8) = pk;
    }
}

// ------- prep: w (O,CIN,81) f32 -> wt [81][CIN/16][COUT][16] bf16 ------------------
template <int CIN>
__global__ __launch_bounds__(256) void cvt_w(const float* __restrict__ w,
                                             __bf16* __restrict__ wt) {
    constexpr int COUT = 8192 / CIN;
    constexpr int LOGC = (CIN == 64) ? 7 : 6;   // log2(COUT)
    const int tap = blockIdx.x;                 // 0..80
    __bf16* dst = wt + (size_t)tap * 8192;
    #pragma unroll
    for (int it = 0; it < 32; ++it) {
        const int i  = it * 256 + threadIdx.x;  // kg*(COUT*16) + o*16 + cl
        const int cl = i & 15;
        const int o  = (i >> 4) & (COUT - 1);
        const int kg = i >> (4 + LOGC);
        dst[i] = (__bf16)w[(size_t)(o * CIN + kg * 16 + cl) * 81 + tap];
    }
}

// ---------------- fused conv4d (implicit GEMM, 32x32x16 bf16 MFMA) -----------------
// One wave per block. Wave tile M=128 (rr=4, v-span 4), N=32.
// Per unit (= one (kt,ku) stage x 32 channels): 6 groups g=(ks,kw), each
// {3x B-load, 6x A-load direct from chunk-planar global, 12 MFMA}.
template <int CIN, int COUT, int NSPL, bool RELU>
__global__ __launch_bounds__(64, 4) void conv4d_mfma(
    const __bf16* __restrict__ in_t,   // chunk-planar activations
    const __bf16* __restrict__ wt,     // [81][CIN/16][COUT][16]
    const float* __restrict__ bias,    // [COUT]
    __bf16* __restrict__ out_bf,       // chunk-planar (RELU path)
    float* __restrict__ out_f)         // [2][COUT][65536]  (else)
{
    constexpr int KST   = CIN / 16;
    constexpr int UNITS = CIN / 32;
    constexpr int LOGU  = (UNITS == 2) ? 1 : 2;
    constexpr int VROWB = CIN * 64;               // bytes per v row (CIN*32 el)

    const int tid = threadIdx.x;                  // 0..63 (one wave)
    const int l31 = tid & 31;
    const int hl  = tid >> 5;

    // grid: xcd(3) | ulo(1) | vg(3) | t(2) | nb(1) | nsp
    const int bid = blockIdx.x;
    const int xcd = bid & 7;
    const int s0  = bid >> 3;
    const int u   = xcd * 2 + (s0 & 1);
    const int vg  = (s0 >> 1) & 7;
    const int t   = (s0 >> 4) & 3;
    const int nb  = (s0 >> 6) & 1;
    const int nsp = (s0 >> 7) & (NSPL - 1);
    const int v0  = vg * 4;
    const int pbase = ((t * 16 + u) * 32 + v0) * 32;

    const char* inb = (const char*)in_t + (size_t)nb * 65536 * CIN * 2;

    // per-lane w-column byte offsets, clamped (edge lanes masked after load)
    int col[3];
    #pragma unroll
    for (int kw = 0; kw < 3; ++kw) {
        int w_in = l31 + kw - 1;
        w_in = w_in < 0 ? 0 : (w_in > 31 ? 31 : w_in);
        col[kw] = w_in * 16;
    }
    const bool klo = (l31 == 0);                  // kw=0 edge lane
    const bool khi = (l31 == 31);                 // kw=2 edge lane
    // uniform v-row validity (rows j=0..5 -> v_in = v0-1+j; clamped offset)
    const bool vok0 = (vg != 0);
    const bool vok5 = (vg != 7);
    int rowoff[6];
    #pragma unroll
    for (int j = 0; j < 6; ++j) {
        int v_in = v0 - 1 + j;
        v_in = v_in < 0 ? 0 : (v_in > 31 ? 31 : v_in);
        rowoff[j] = v_in * VROWB;
    }

    // B lane pointer: o = nsp*32 + l31; + hl*8 within the 16-ch group
    const int o = nsp * 32 + l31;
    const __bf16* wlane = wt + (size_t)o * 16 + hl * 8;

    // ---- valid (kt,ku) stage list packed as 4-bit codes (registers only) ----
    unsigned long long pack = 0;
    int nst = 0;
    #pragma unroll
    for (int kt = 0; kt < 3; ++kt) {
        const int t_in = t + kt - 1;
        if ((unsigned)t_in >= 4u) continue;
        #pragma unroll
        for (int ku = 0; ku < 3; ++ku) {
            const int u_in = u + ku - 1;
            if ((unsigned)u_in >= 16u) continue;
            pack |= (unsigned long long)(kt * 3 + ku) << (4 * nst);
            ++nst;
        }
    }
    const int U = nst * UNITS;

    f32x16 acc[4];
    #pragma unroll
    for (int mt = 0; mt < 4; ++mt)
        #pragma unroll
        for (int i = 0; i < 16; ++i)
            acc[mt][i] = 0.f;

    bf16x8 z8;
    #pragma unroll
    for (int e = 0; e < 8; ++e) z8[e] = (__bf16)0.0f;

    #pragma unroll 1
    for (int i = 0; i < U; ++i) {
        const int st   = i >> LOGU;
        const int ch   = i & (UNITS - 1);
        const int code = (int)((pack >> (st * 4)) & 15);
        const int kt   = (code * 11) >> 5;        // code/3 for code<9
        const int ku   = code - kt * 3;
        const int tapb = code * 9;
        // uniform byte base of this unit's 4 chunk-planes
        const char* ub = inb +
            (size_t)(((t + kt - 1) * 16 + (u + ku - 1)) * 1024 * CIN +
                     ch * 1024) * 2;

        // one group: 3 B loads, 6 A loads (masked), 12 MFMA
        auto group = [&](int ks, int kw, bool maskall) {
            const int ksg = ch * 2 + ks;
            bf16x8 bv[3];
            #pragma unroll
            for (int kv = 0; kv < 3; ++kv) {
                const int wo = ((tapb + kv * 3 + kw) * KST + ksg) * (COUT * 16);
                bv[kv] = *(const bf16x8*)(wlane + wo);
            }
            const int loff = (ks * 2 + hl) * 512 + col[kw];
            bf16x8 af[6];
            #pragma unroll
            for (int j = 0; j < 6; ++j)
                af[j] = *(const bf16x8*)(ub + rowoff[j] + loff);
            // halo masking: edge lanes (kw 0/2) and OOB v rows (j 0/5)
            const bool kl = maskall ? ((kw == 0) ? klo : khi) : false;
            #pragma unroll
            for (int j = 0; j < 6; ++j) {
                bool dead = kl;
                if (j == 0) dead = dead || !vok0;
                if (j == 5) dead = dead || !vok5;
                if (maskall || j == 0 || j == 5)
                    af[j] = dead ? z8 : af[j];
            }
            #pragma unroll
            for (int kv = 0; kv < 3; ++kv)
                #pragma unroll
                for (int rr = 0; rr < 4; ++rr)
                    acc[rr] = __builtin_amdgcn_mfma_f32_32x32x16_bf16(
                        af[rr + kv], bv[kv], acc[rr], 0, 0, 0);
        };

        group(0, 0, true);
        group(0, 1, false);
        group(0, 2, true);
        group(1, 0, true);
        group(1, 1, false);
        group(1, 2, true);
    }

    // ---- epilogue: C/D 32x32: col = lane&31, row = (reg&3) + 8*(reg>>2) + 4*hl ----
    {
        const float bvls = bias[o];
        #pragma unroll
        for (int rr = 0; rr < 4; ++rr) {
            const int pb = pbase + rr * 32;
            if constexpr (RELU) {
                #pragma unroll
                for (int rg = 0; rg < 4; ++rg)
                    #pragma unroll
                    for (int j = 0; j < 4; ++j) {
                        float v = acc[rr][rg * 4 + j] + bvls;
                        v = v > 0.f ? v : 0.f;
                        const int p = pb + j + 8 * rg + 4 * hl;
                        const int vv = (p >> 5) & 31, ww = p & 31, tu = p >> 10;
                        out_bf[(size_t)nb * 65536 * COUT +
                               (size_t)(tu * 32 + vv) * (32 * COUT) +
                               (o >> 3) * 256 + ww * 8 + (o & 7)] = (__bf16)v;
                    }
            } else {
                #pragma unroll
                for (int rg = 0; rg < 4; ++rg) {
                    f32x4 sv;
                    #pragma unroll
                    for (int j = 0; j < 4; ++j)
                        sv[j] = acc[rr][rg * 4 + j] + bvls;
                    const int p = pb + 8 * rg + 4 * hl;
                    *(f32x4*)(out_f + ((size_t)nb * COUT + o) * 65536 + p) = sv;
                }
            }
        }
    }
}

extern "C" void kernel_launch(void* const* d_in, const int* in_sizes, int n_in,
                              void* d_out, int out_size, void* d_ws, size_t ws_size,
                              hipStream_t stream) {
    const float* x  = (const float*)d_in[0];
    const float* w1 = (const float*)d_in[1];
    const float* b1 = (const float*)d_in[2];
    const float* w2 = (const float*)d_in[3];
    const float* b2 = (const float*)d_in[4];
    float* out = (float*)d_out;

    char* ws = (char*)d_ws;
    __bf16* x_t = (__bf16*)ws;                               // 16,777,216 B
    __bf16* h_t = (__bf16*)(ws + 16777216);                  // 33,554,432 B
    __bf16* w1t = (__bf16*)(ws + 50331648);                  //  1,327,104 B
    __bf16* w2t = (__bf16*)(ws + 51658752);                  //  1,327,104 B

    cvt_x<<<dim3(1024, 2), 256, 0, stream>>>(x, x_t);
    cvt_w<64><<<81, 256, 0, stream>>>(w1, w1t);
    cvt_w<128><<<81, 256, 0, stream>>>(w2, w2t);

    // conv1: 1-wave blocks, M=128 N=32, COUT split 4 -> grid 4096 (4 w/SIMD)
    conv4d_mfma<64, 128, 4, true><<<4096, 64, 0, stream>>>(x_t, w1t, b1, h_t,
                                                           nullptr);
    // conv2: 1-wave blocks, M=128 N=32, COUT split 2 -> grid 2048 (2 w/SIMD)
    conv4d_mfma<128, 64, 2, false><<<2048, 64, 0, stream>>>(h_t, w2t, b2,
                                                            nullptr, out);
}

// Round 10
// 382.677 us; speedup vs baseline: 1.2928x; 1.2928x over previous
//
#include <hip/hip_runtime.h>

// ConvMlp4d: conv4d(64->128) + bias + relu -> conv4d(128->64) + bias.
// R20 = R14 + per-block phase stagger.
//   Decisive evidence (R10-R19): MfmaUtil x dur == const (~60 us/conv) across
//   8 structures (LDS/no-LDS, barriers/none, occupancy 9->32%, all prefetch
//   schemes); per-wave duty halves when waves double -> co-resident waves'
//   MFMA/stall windows are ALIGNED IN TIME. Cause: every block starts at t=0
//   and runs the identical instruction stream with identical per-iteration
//   wall (~5.4k cyc) -> convoys are phase-locked by construction, and the
//   matrix pipe can never exceed single-wave duty (~43%).
//   Fix: per-block pseudo-random start delay 0..7 x s_sleep(15) (~0-6.7k cyc,
//   spans one iteration wall), hashed from bid, after DMA(0) issue. Blocks
//   interleave their MFMA windows into each other's stall windows.
//   Base structure (R14): per iteration
//     [vmcnt(0)+barrier (DMA(i) had full-unit cover)]
//     [ldB x18 for unit i]  [issue DMA(i+1)]  [6x: ldA(g+1) || 12-MFMA(g)]
//   - DMA unconditional (7 insts): halo lanes read a zero page; LDS padded
//     to 896 slots/buffer so overflow lanes land in never-read pad
//   - both convs: 128-thr blocks, 2 waves, wave tile M=128 (rr=4) x N=32,
//     VSPAN=4, ROWS=6; conv1 grid 2048 (COUT split 2), conv2 grid 1024
//   ws: x_t bf16 [2][65536][64] | h_t bf16 [2][65536][128] (chunk-planar:
//       [nb][tu][v][chunk=c/8][w][c%8])
//       w1t bf16 [81][4][128][16] | w2t bf16 [81][8][64][16] | zpage 4KB

using bf16x8 = __attribute__((ext_vector_type(8))) __bf16;
using f32x16 = __attribute__((ext_vector_type(16))) float;
using f32x4  = __attribute__((ext_vector_type(4))) float;

typedef __attribute__((address_space(1))) const void as1_void;
typedef __attribute__((address_space(3))) void as3_void;
__device__ __forceinline__ void gload_lds16(const void* g, void* l) {
    __builtin_amdgcn_global_load_lds((as1_void*)g, (as3_void*)l, 16, 0, 0);
}
#define SBAR() __builtin_amdgcn_sched_barrier(0)

// ------- prep: x (2,64,65536) f32 -> x_t chunk-planar bf16; zero the zpage --------
__global__ __launch_bounds__(256) void cvt_x(const float* __restrict__ x,
                                             __bf16* __restrict__ x_t,
                                             __bf16* __restrict__ zp) {
    __shared__ float lt[64][65];
    if (blockIdx.x == 0 && blockIdx.y == 0)
        *(uint4*)((char*)zp + threadIdx.x * 16) = make_uint4(0u, 0u, 0u, 0u);
    const int nb = blockIdx.y;
    const int p0 = blockIdx.x * 64;
    const int tu = p0 >> 10;
    const float* src = x + (size_t)nb * 64 * 65536;
    __bf16* dst = x_t + (size_t)nb * 65536 * 64;
    #pragma unroll
    for (int i = 0; i < 16; ++i) {
        int idx = i * 256 + threadIdx.x;
        int c = idx >> 6, p = idx & 63;
        lt[c][p] = src[(size_t)c * 65536 + p0 + p];
    }
    __syncthreads();
    #pragma unroll
    for (int it = 0; it < 2; ++it) {
        int idx = it * 256 + threadIdx.x;
        int pl = idx & 63;
        int chunk = idx >> 6;
        int p = p0 + pl;
        int v = (p >> 5) & 31, w = p & 31;
        bf16x8 pk;
        #pragma unroll
        for (int e = 0; e < 8; ++e)
            pk[e] = (__bf16)lt[chunk * 8 + e][pl];
        *(bf16x8*)(dst + (size_t)(tu * 32 + v) * 2048 + chunk * 256 + w * 8) = pk;
    }
}

// ------- prep: w (O,CIN,81) f32 -> wt [81][CIN/16][COUT][16] bf16 ------------------
template <int CIN>
__global__ __launch_bounds__(256) void cvt_w(const float* __restrict__ w,
                                             __bf16* __restrict__ wt) {
    constexpr int COUT = 8192 / CIN;
    constexpr int LOGC = (CIN == 64) ? 7 : 6;   // log2(COUT)
    const int tap = blockIdx.x;                 // 0..80
    __bf16* dst = wt + (size_t)tap * 8192;
    #pragma unroll
    for (int it = 0; it < 32; ++it) {
        const int i  = it * 256 + threadIdx.x;  // kg*(COUT*16) + o*16 + cl
        const int cl = i & 15;
        const int o  = (i >> 4) & (COUT - 1);
        const int kg = i >> (4 + LOGC);
        dst[i] = (__bf16)w[(size_t)(o * CIN + kg * 16 + cl) * 81 + tap];
    }
}

// ---------------- fused conv4d (implicit GEMM, 32x32x16 bf16 MFMA) -----------------
// Block 128 thr = 2 waves (gni = wave). Wave tile M=128 (rr=4), N=32.
// Block tile M=128 (v-span 4), N=64; conv1 splits COUT 128 into 2 n-blocks.
// Staging unit = one (kt,ku) stage x 32 channels: LDS [6 rows][chunk4][wp34] 16B
// slots, padded to 896/buffer; ping-pong.
template <int CIN, int COUT, int NSPLIT, bool RELU>
__global__ __launch_bounds__(128, 2) void conv4d_mfma(
    const __bf16* __restrict__ in_t,   // chunk-planar activations
    const __bf16* __restrict__ wt,     // [81][CIN/16][COUT][16]
    const float* __restrict__ bias,    // [COUT]
    __bf16* __restrict__ out_bf,       // chunk-planar (RELU path)
    float* __restrict__ out_f,         // [2][COUT][65536]  (else)
    const __bf16* __restrict__ zpage)  // 4KB of zeros
{
    constexpr int KST     = CIN / 16;
    constexpr int UNITS   = CIN / 32;
    constexpr int LOGU    = (UNITS == 2) ? 1 : 2;
    constexpr int SLOTS   = 6 * 136;               // 816 valid 16B slots
    constexpr int SLOTS_P = 896;                   // padded to 7*128
    constexpr int RNDS    = 7;                     // DMA rounds (128 thr each)
    constexpr int BUFB_P  = SLOTS_P * 16;          // 14336 B

    __shared__ __bf16 tile[2 * SLOTS_P * 8];       // ping-pong, 28672 B

    const int tid  = threadIdx.x;                  // 0..127
    const int lane = tid & 63;
    const int l31  = lane & 31;
    const int hl   = lane >> 5;
    const int wv   = tid >> 6;                     // 0..1 = gni

    // grid: xcd(3) | ulo(1) | vg(3) | t(2) | nb(1) | nsp(log2 NSPLIT)
    const int bid = blockIdx.x;
    const int xcd = bid & 7;
    const int s0  = bid >> 3;
    const int u   = xcd * 2 + (s0 & 1);
    const int vg  = (s0 >> 1) & 7;
    const int t   = (s0 >> 4) & 3;
    const int nb  = (s0 >> 6) & 1;
    const int nsp = (s0 >> 7) & (NSPLIT - 1);
    const int v0  = vg * 4;
    const int pbase = ((t * 16 + u) * 32 + v0) * 32;

    const __bf16* inb = in_t + (size_t)nb * 65536 * CIN;

    // ---- per-lane staging offsets (slot = r*128 + tid), chunk-planar global ----
    int goff[RNDS];
    #pragma unroll
    for (int r = 0; r < RNDS; ++r) {
        const int slot = r * 128 + tid;            // 16B-chunk slot
        const int row  = slot / 136;               // LDS [6][chunk4][wp34]
        const int rem  = slot - row * 136;
        const int chunk = rem / 34;
        const int wp   = rem - chunk * 34;
        const int v_in = v0 - 1 + row;
        const int w_in = wp - 1;
        const bool ok = (slot < SLOTS) && ((unsigned)v_in < 32u) &&
                        ((unsigned)w_in < 32u);
        goff[r] = ok ? (v_in * (CIN * 32) + chunk * 256 + w_in * 8) : -1;
    }

    // A-read lane base (16B slots): slot = j*136 + (ks*2+hl)*34 + l31 + kw
    const int lane_base = hl * 34 + l31;
    const bf16x8* tile16 = (const bf16x8*)tile;

    // B lane pointer: o = nsp*64 + gni*32 + l31; + hl*8 within the 16-ch group
    const int o = nsp * 64 + wv * 32 + l31;
    const __bf16* wlane = wt + (size_t)o * 16 + hl * 8;

    // ---- valid (kt,ku) stage list (block-uniform) ----
    int sb[9], tb0[9], nst = 0;
    #pragma unroll
    for (int kt = 0; kt < 3; ++kt) {
        const int t_in = t + kt - 1;
        if ((unsigned)t_in >= 4u) continue;
        #pragma unroll
        for (int ku = 0; ku < 3; ++ku) {
            const int u_in = u + ku - 1;
            if ((unsigned)u_in >= 16u) continue;
            sb[nst]  = (t_in * 16 + u_in) * 1024 * CIN;
            tb0[nst] = (kt * 3 + ku) * 9;
            ++nst;
        }
    }
    const int U = nst * UNITS;

    f32x16 acc[4];
    #pragma unroll
    for (int mt = 0; mt < 4; ++mt)
        #pragma unroll
        for (int i = 0; i < 16; ++i)
            acc[mt][i] = 0.f;

    // DMA issue for unit j into buffer `buf` (UNCONDITIONAL: 7 insts/wave;
    // halo/pad lanes read the zero page)
    auto issue = [&](int buf, int j) {
        const int st = j >> LOGU, ch = j & (UNITS - 1);
        const __bf16* gb = inb + sb[st] + ch * 1024;   // unit = 4 chunk-planes
        char* lb = ((char*)tile) + buf * BUFB_P + wv * 1024;
        #pragma unroll
        for (int r = 0; r < RNDS; ++r) {
            const __bf16* ga = (goff[r] >= 0) ? gb + goff[r] : zpage;
            gload_lds16(ga, lb + r * 2048);
        }
    };

    // A-fragment group load (6x ds_read_b128); g = (ks*3 + kw)
    auto ldA = [&](const bf16x8* tb, int g, bf16x8 (&af)[6]) {
        const int ks = g / 3, kw = g % 3;
        #pragma unroll
        for (int j = 0; j < 6; ++j)
            af[j] = tb[j * 136 + ks * 68 + kw];
    };
    // B-fragment group load (3x global 16B, L2-resident weights)
    auto ldB = [&](int tapb, int ch, int g, bf16x8 (&bv)[3]) {
        const int ks = g / 3, kw = g % 3;
        const int ksg = ch * 2 + ks;
        #pragma unroll
        for (int kv = 0; kv < 3; ++kv) {
            const int wo = ((tapb + kv * 3 + kw) * KST + ksg) * (COUT * 16);
            bv[kv] = *(const bf16x8*)(wlane + wo);
        }
    };
    // one (ks,kw) group's MFMA cluster
    auto mfma12 = [&](bf16x8 (&af)[6], bf16x8 (&bv)[3]) {
        #pragma unroll
        for (int kv = 0; kv < 3; ++kv)
            #pragma unroll
            for (int rr = 0; rr < 4; ++rr)
                acc[rr] = __builtin_amdgcn_mfma_f32_32x32x16_bf16(
                    af[rr + kv], bv[kv], acc[rr], 0, 0, 0);
    };

    issue(0, 0);

    // ---- phase-stagger (the R20 change): decorrelate the per-block convoy.
    // All blocks otherwise start together and share an identical per-iteration
    // wall (~5.4k cyc), so co-resident waves' MFMA and stall windows align and
    // the matrix pipe is capped at single-wave duty (R10-R19 invariant).
    // Hash(bid) -> 0..7 sleeps of ~960 cyc = 0..6.7k cyc (~one iteration).
    // DMA(0) above warms during the sleep.
    {
        const int dl = (bid ^ (bid >> 3) ^ (bid >> 6)) & 7;
        #pragma unroll 1
        for (int k = 0; k < dl; ++k)
            __builtin_amdgcn_s_sleep(15);
    }

    #pragma unroll 1
    for (int i = 0; i < U; ++i) {
        // DMA(i) was issued a full unit ago (or in the prologue): cheap wait.
        asm volatile("s_waitcnt vmcnt(0)" ::: "memory");
        __builtin_amdgcn_s_barrier();

        const int st = i >> LOGU, ch = i & (UNITS - 1);
        const int tapb = tb0[st];
        const bf16x8* tb = tile16 + (i & 1) * SLOTS_P + lane_base;

        // B for THIS unit, loaded up front (L2-resident; g0 waits ~300cy,
        // later groups fully covered by earlier clusters)
        bf16x8 bvv[6][3];
        #pragma unroll
        for (int g = 0; g < 6; ++g)
            ldB(tapb, ch, g, bvv[g]);
        SBAR();
        // DMA(i+1) AFTER all B loads: it is younger than every vmem value
        // consumed this iteration, so no bv-consumer wait retires it.
        if (i + 1 < U) issue((i + 1) & 1, i + 1);
        SBAR();

        bf16x8 afA[6], afB[6];
        // groups g=(ks,kw): g0=(0,0) g1=(0,1) g2=(0,2) g3=(1,0) g4=(1,1) g5=(1,2)
        ldA(tb, 0, afA);
        ldA(tb, 1, afB);
        mfma12(afA, bvv[0]);
        ldA(tb, 2, afA);
        mfma12(afB, bvv[1]);
        ldA(tb, 3, afB);
        mfma12(afA, bvv[2]);
        ldA(tb, 4, afA);
        mfma12(afB, bvv[3]);
        ldA(tb, 5, afB);
        mfma12(afA, bvv[4]);
        mfma12(afB, bvv[5]);
    }

    // ---- epilogue: C/D 32x32: col = lane&31, row = (reg&3) + 8*(reg>>2) + 4*hl ----
    {
        const float bvls = bias[o];
        #pragma unroll
        for (int rr = 0; rr < 4; ++rr) {
            const int pb = pbase + rr * 32;
            if constexpr (RELU) {
                #pragma unroll
                for (int rg = 0; rg < 4; ++rg)
                    #pragma unroll
                    for (int j = 0; j < 4; ++j) {
                        float v = acc[rr][rg * 4 + j] + bvls;
                        v = v > 0.f ? v : 0.f;
                        const int p = pb + j + 8 * rg + 4 * hl;
                        const int vv = (p >> 5) & 31, ww = p & 31, tu = p >> 10;
                        out_bf[(size_t)nb * 65536 * COUT +
                               (size_t)(tu * 32 + vv) * (32 * COUT) +
                               (o >> 3) * 256 + ww * 8 + (o & 7)] = (__bf16)v;
                    }
            } else {
                #pragma unroll
                for (int rg = 0; rg < 4; ++rg) {
                    f32x4 sv;
                    #pragma unroll
                    for (int j = 0; j < 4; ++j)
                        sv[j] = acc[rr][rg * 4 + j] + bvls;
                    const int p = pb + 8 * rg + 4 * hl;
                    *(f32x4*)(out_f + ((size_t)nb * COUT + o) * 65536 + p) = sv;
                }
            }
        }
    }
}

extern "C" void kernel_launch(void* const* d_in, const int* in_sizes, int n_in,
                              void* d_out, int out_size, void* d_ws, size_t ws_size,
                              hipStream_t stream) {
    const float* x  = (const float*)d_in[0];
    const float* w1 = (const float*)d_in[1];
    const float* b1 = (const float*)d_in[2];
    const float* w2 = (const float*)d_in[3];
    const float* b2 = (const float*)d_in[4];
    float* out = (float*)d_out;

    char* ws = (char*)d_ws;
    __bf16* x_t = (__bf16*)ws;                               // 16,777,216 B
    __bf16* h_t = (__bf16*)(ws + 16777216);                  // 33,554,432 B
    __bf16* w1t = (__bf16*)(ws + 50331648);                  //  1,327,104 B
    __bf16* w2t = (__bf16*)(ws + 51658752);                  //  1,327,104 B
    __bf16* zpg = (__bf16*)(ws + 52985856);                  //      4,096 B

    cvt_x<<<dim3(1024, 2), 256, 0, stream>>>(x, x_t, zpg);
    cvt_w<64><<<81, 256, 0, stream>>>(w1, w1t);
    cvt_w<128><<<81, 256, 0, stream>>>(w2, w2t);

    // conv1: 128-thr blocks, M=128 N=64, COUT split 2 -> grid 2048
    conv4d_mfma<64, 128, 2, true><<<2048, 128, 0, stream>>>(x_t, w1t, b1, h_t,
                                                            nullptr, zpg);
    // conv2: 128-thr blocks, M=128 N=64, grid 1024 (5 blocks/CU LDS-capped)
    conv4d_mfma<128, 64, 1, false><<<1024, 128, 0, stream>>>(h_t, w2t, b2,
                                                             nullptr, out, zpg);
}